// Round 1
// baseline (2145.435 us; speedup 1.0000x reference)
//
#include <hip/hip_runtime.h>
#include <cstdint>
#include <cstddef>

#define U_N 30000
#define I_N 60000
#define G_N 2000
#define N_UI 90000
#define N_ALL 92000
#define LDU 30016   // U_N padded to mult of 32 (bf16 zero pad)
#define LDI 60000   // already mult of 32
#define LDG 2016    // G_N padded to mult of 32

typedef __bf16 v8bf __attribute__((ext_vector_type(8)));
typedef float  v4f  __attribute__((ext_vector_type(4)));
typedef unsigned short u16x8 __attribute__((ext_vector_type(8)));
typedef unsigned short u16x4 __attribute__((ext_vector_type(4)));

__device__ __forceinline__ float ldf(const float* p){ return *p; }
__device__ __forceinline__ float ldf(const unsigned short* p){
  union { unsigned int i; float f; } x; x.i = ((unsigned int)*p) << 16; return x.f;
}
__device__ __forceinline__ unsigned short f2bf(float f){
  return __builtin_bit_cast(unsigned short, (__bf16)f);
}

// global -> LDS async copy, 16B per lane. LDS dest must be wave-uniform;
// HW writes lds + lane*16. Global src is per-lane.
__device__ __forceinline__ void gload16(const void* g, void* l){
  __builtin_amdgcn_global_load_lds(
      (const __attribute__((address_space(1))) void*)g,
      (__attribute__((address_space(3))) void*)l, 16, 0, 0);
}

// ---------------- dtype detector ----------------
__global__ void detect_k(const unsigned int* raw, int* flag){
  __shared__ int s;
  if (threadIdx.x == 0) s = 0;
  __syncthreads();
  unsigned int v = raw[threadIdx.x];
  if ((v >> 15) & 1u) s = 1;          // benign same-value race
  __syncthreads();
  if (threadIdx.x == 0) *flag = (s ? 0 : 1);   // 0 = f32, 1 = bf16
}

// ---------------- init: final <- concat(user,item); embT (bf16, transposed) ----------------
template<typename T>
__global__ void init_emb_k(const int* flag, const T* ue, const T* ie,
                           float* finalbuf, __bf16* embT_u, __bf16* embT_i){
  constexpr int WANT = (sizeof(T)==2) ? 1 : 0;
  if (*flag != WANT) return;
  __shared__ float tile[64*65];
  int n0 = blockIdx.x * 64;
  int tid = threadIdx.x;
  #pragma unroll
  for (int i=0;i<16;i++){
    int idx = i*256 + tid;
    int nl = idx >> 6, e = idx & 63;
    int n = n0 + nl;
    if (n < N_UI){
      float v = (n < U_N) ? ldf(ue + (size_t)n*64 + e)
                          : ldf(ie + (size_t)(n - U_N)*64 + e);
      finalbuf[(size_t)n*64 + e] = v;
      tile[e*65 + nl] = v;
    }
  }
  __syncthreads();
  int e = tid >> 2, c = tid & 3;
  int r0 = n0 + 16*c;
  if (r0 + 16 <= N_UI){
    v8bf o0, o1;
    #pragma unroll
    for (int i=0;i<8;i++) o0[i] = (__bf16)tile[e*65 + 16*c + i];
    #pragma unroll
    for (int i=0;i<8;i++) o1[i] = (__bf16)tile[e*65 + 16*c + 8 + i];
    __bf16* dst = (r0 < U_N) ? (embT_u + (size_t)e*LDU + r0)
                             : (embT_i + (size_t)e*LDI + (r0 - U_N));
    *(v8bf*)dst = o0;
    *(v8bf*)(dst + 8) = o1;
  }
}

// final_he init + zero embT_u's k-pad columns
template<typename T>
__global__ void init_group_k(const int* flag, const T* ge, float* finalbuf, __bf16* embT_u){
  constexpr int WANT = (sizeof(T)==2) ? 1 : 0;
  if (*flag != WANT) return;
  int idx = blockIdx.x*256 + threadIdx.x;
  if (idx < G_N*64) finalbuf[(size_t)N_UI*64 + idx] = ldf(ge + idx);
  if (idx < 64*16){
    int e = idx >> 4, i = idx & 15;
    embT_u[(size_t)e*LDU + U_N + i] = (__bf16)0.0f;
  }
}

// ---------------- MFMA GEMM: C^T[e][row] = sum_k XT[e][k] * H[row][k] ----------------
// H staged through LDS in 1KB-contiguous-per-row chunks (DRAM-friendly),
// 16B-chunk XOR swizzle (pre-swizzled global src, linear LDS dest) so the
// ds_read_b128 fragment reads are bank-uniform.
// EPI 0: atomicAdd into msgT (f32 [64][ldC]), k-split   EPI 1: final += , embT <- bf16
template<typename T, int EPI>
__launch_bounds__(256)
__global__ void gemm_k(const int* flag,
                       const T* __restrict__ H, int ldH, int M, int K,
                       const __bf16* __restrict__ XT, int ldX, int kLen,
                       float* __restrict__ C, int ldC,
                       __bf16* __restrict__ embT_u, __bf16* __restrict__ embT_i)
{
  constexpr int WANT = (sizeof(T)==2) ? 1 : 0;
  if (*flag != WANT) return;
  constexpr int EPC = 16 / (int)sizeof(T);   // elements per 16B chunk (4 f32 / 8 bf16)
  constexpr int KC  = 64 * EPC;              // stage depth in elements (256 / 512); row = 1KB
  // 64KB staging tile + (EPI1) aliased 64x65 f32 epilogue tile (66,560B)
  __shared__ __align__(16) char smem[66560];

  int tid = threadIdx.x;
  int w = tid >> 6, lane = tid & 63;
  int q = lane >> 4, t = lane & 15;
  int m0 = blockIdx.x * 64;
  int kb = blockIdx.y * kLen;
  int kbe = min(kb + kLen, K);
  int rl = 16*w + t;                 // local row (wave w owns rows 16w..16w+15)
  int rowB = m0 + rl;
  int swz = rl & 7;
  char* myrow = smem + (size_t)rl * 1024;
  char* stg   = smem + (size_t)(16*w) * 1024;
  const __bf16* ap0 = XT + (size_t)t * ldX;
  const __bf16* a1p = ap0 + (size_t)16 * ldX;
  const __bf16* a2p = ap0 + (size_t)32 * ldX;
  const __bf16* a3p = ap0 + (size_t)48 * ldX;
  const int kmax = K - EPC;

  v4f z = {0.0f, 0.0f, 0.0f, 0.0f};
  v4f acc[4] = {z, z, z, z};

  for (int kc = kb; kc < kbe; kc += KC){
    // ---- stage: each wave loads its own 16 rows, 1KB contiguous per row ----
    #pragma unroll
    for (int r = 0; r < 16; r++){
      int grow = m0 + 16*w + r; if (grow >= M) grow = M - 1;
      int ce = lane ^ ((16*w + r) & 7);          // pre-swizzled source chunk
      int koff = kc + ce * EPC;
      if (koff > kmax) koff = kmax;              // clamped chunks are all k>=K -> masked
      gload16(H + (size_t)grow * ldH + koff, stg + (size_t)r * 1024);
    }
    __syncthreads();   // drains vmcnt -> tile valid; also orders prior ds_reads vs rewrite

    int stageLen = min(KC, kbe - kc);
    int nFull = stageLen >> 5;
    #pragma unroll 4
    for (int it = 0; it < nFull; ++it){
      int kl  = (it << 5) + q*8;     // element offset within stage
      int klg = kc + kl;             // global k
      v8bf bfr;
      if constexpr (sizeof(T) == 2){
        int ch = (kl >> 3) ^ swz;
        bfr = __builtin_bit_cast(v8bf, *(const u16x8*)(myrow + (ch << 4)));
      } else {
        int g0 = kl >> 2;
        float4 x0 = *(const float4*)(myrow + (((g0    ) ^ swz) << 4));
        float4 x1 = *(const float4*)(myrow + (((g0 + 1) ^ swz) << 4));
        bfr[0]=(__bf16)x0.x; bfr[1]=(__bf16)x0.y; bfr[2]=(__bf16)x0.z; bfr[3]=(__bf16)x0.w;
        bfr[4]=(__bf16)x1.x; bfr[5]=(__bf16)x1.y; bfr[6]=(__bf16)x1.z; bfr[7]=(__bf16)x1.w;
      }
      v8bf a0 = *(const v8bf*)(ap0 + klg);
      v8bf a1 = *(const v8bf*)(a1p + klg);
      v8bf a2 = *(const v8bf*)(a2p + klg);
      v8bf a3 = *(const v8bf*)(a3p + klg);
      acc[0] = __builtin_amdgcn_mfma_f32_16x16x32_bf16(a0, bfr, acc[0], 0, 0, 0);
      acc[1] = __builtin_amdgcn_mfma_f32_16x16x32_bf16(a1, bfr, acc[1], 0, 0, 0);
      acc[2] = __builtin_amdgcn_mfma_f32_16x16x32_bf16(a2, bfr, acc[2], 0, 0, 0);
      acc[3] = __builtin_amdgcn_mfma_f32_16x16x32_bf16(a3, bfr, acc[3], 0, 0, 0);
    }
    if (stageLen & 31){               // masked tail iteration (rare)
      int kk = nFull << 5;
      v8bf bfr;
      #pragma unroll
      for (int j = 0; j < 8; j++){
        int k = kk + q*8 + j;
        if (k < stageLen){
          if constexpr (sizeof(T) == 2){
            bfr[j] = *(const __bf16*)(myrow + ((((k >> 3) ^ swz)) << 4) + ((k & 7) << 1));
          } else {
            bfr[j] = (__bf16)(*(const float*)(myrow + ((((k >> 2) ^ swz)) << 4) + ((k & 3) << 2)));
          }
        } else bfr[j] = (__bf16)0.0f;
      }
      int klg = kc + kk + q*8;
      v8bf a0 = *(const v8bf*)(ap0 + klg);
      v8bf a1 = *(const v8bf*)(a1p + klg);
      v8bf a2 = *(const v8bf*)(a2p + klg);
      v8bf a3 = *(const v8bf*)(a3p + klg);
      acc[0] = __builtin_amdgcn_mfma_f32_16x16x32_bf16(a0, bfr, acc[0], 0, 0, 0);
      acc[1] = __builtin_amdgcn_mfma_f32_16x16x32_bf16(a1, bfr, acc[1], 0, 0, 0);
      acc[2] = __builtin_amdgcn_mfma_f32_16x16x32_bf16(a2, bfr, acc[2], 0, 0, 0);
      acc[3] = __builtin_amdgcn_mfma_f32_16x16x32_bf16(a3, bfr, acc[3], 0, 0, 0);
    }
    __syncthreads();   // before next-stage overwrite (and before epilogue smem reuse)
  }

  if constexpr (EPI == 0){
    if (rowB < M){
      #pragma unroll
      for (int g=0; g<4; g++){
        #pragma unroll
        for (int r=0;r<4;r++){
          int e = 16*g + 4*q + r;
          atomicAdd(C + (size_t)e*ldC + rowB, acc[g][r]);
        }
      }
    }
  } else {
    float* etile = (float*)smem;       // 64x65 f32, aliases staging tile (done with it)
    int rl0 = rl;
    #pragma unroll
    for (int g=0; g<4; g++){
      #pragma unroll
      for (int r=0;r<4;r++)
        etile[rl0*65 + 16*g + 4*q + r] = acc[g][r];
    }
    __syncthreads();
    {
      int rr = tid >> 2, e0 = (tid & 3)*16;
      int row = m0 + rr;
      if (row < M){
        float* op = C + (size_t)row*64 + e0;
        #pragma unroll
        for (int jj=0;jj<4;jj++){
          float4 v = *(float4*)(op + jj*4);
          v.x += etile[rr*65 + e0 + jj*4 + 0];
          v.y += etile[rr*65 + e0 + jj*4 + 1];
          v.z += etile[rr*65 + e0 + jj*4 + 2];
          v.w += etile[rr*65 + e0 + jj*4 + 3];
          *(float4*)(op + jj*4) = v;
        }
      }
    }
    {
      int e = tid >> 2, c = tid & 3;
      int r0 = m0 + 16*c;
      if (r0 + 16 <= M){
        v8bf o0, o1;
        #pragma unroll
        for (int i=0;i<8;i++) o0[i] = (__bf16)etile[(16*c + i)*65 + e];
        #pragma unroll
        for (int i=0;i<8;i++) o1[i] = (__bf16)etile[(16*c + 8 + i)*65 + e];
        __bf16* dst = (r0 < U_N) ? (embT_u + (size_t)e*LDU + r0)
                                 : (embT_i + (size_t)e*LDI + (r0 - U_N));
        *(v8bf*)dst = o0;
        *(v8bf*)(dst + 8) = o1;
      }
    }
  }
}

// ---------------- fused attention / MLP over the 2000 groups ----------------
template<typename T>
__global__ void small_k(const int* flag, const float* msgT_u, const float* msgT_i,
                        const T* ge, const T* w1, const T* b1, const T* w2,
                        const T* uw, const T* ub, const T* iw, const T* ib,
                        float* finalbuf, __bf16* gmsgT)
{
  constexpr int WANT = (sizeof(T)==2) ? 1 : 0;
  if (*flag != WANT) return;
  int g = blockIdx.x, e = threadIdx.x;
  __shared__ float um[64], im[64], du[64], di[64], geb[64];
  float u  = msgT_u[(size_t)e*G_N + g];
  float it = msgT_i[(size_t)e*G_N + g];
  um[e] = u; im[e] = it;
  geb[e] = ldf(ge + (size_t)g*64 + e);
  __syncthreads();
  float su = ldf(b1 + e);
  float si = su;
  for (int j=0;j<64;j++){
    float wj = ldf(w1 + j*64 + e);
    su += um[j]*wj;
    si += im[j]*wj;
  }
  su = tanhf(su); si = tanhf(si);
  float w2e = ldf(w2 + e);
  float au = su*w2e, ai = si*w2e;
  #pragma unroll
  for (int off=32; off>0; off>>=1){
    au += __shfl_down(au, off);
    ai += __shfl_down(ai, off);
  }
  au = __shfl(au, 0); ai = __shfl(ai, 0);
  float mx = fmaxf(au, ai);
  float eu = expf(au - mx), ei = expf(ai - mx);
  float inv = 1.0f/(eu + ei);
  float cm = (eu*inv)*u + (ei*inv)*it;
  du[e] = u - cm; di[e] = it - cm;
  __syncthreads();
  float u2  = ldf(ub + e);
  float i2v = ldf(ib + e);
  for (int j=0;j<64;j++){
    u2  += du[j]*ldf(uw + j*64 + e);
    i2v += di[j]*ldf(iw + j*64 + e);
  }
  for (int j=0;j<64;j++){
    u2  += geb[j]*ldf(uw + (64 + j)*64 + e);
    i2v += geb[j]*ldf(iw + (64 + j)*64 + e);
  }
  float msg = u2 + i2v + cm;
  finalbuf[(size_t)(N_UI + g)*64 + e] += msg;
  gmsgT[(size_t)e*LDG + g] = (__bf16)msg;
}

// ---------------- final convert: f32 accumulator -> d_out dtype ----------------
template<typename T>
__global__ void final_k(const int* flag, const float* finalbuf, T* out){
  constexpr int WANT = (sizeof(T)==2) ? 1 : 0;
  if (*flag != WANT) return;
  size_t base = ((size_t)blockIdx.x*256 + threadIdx.x)*4;
  if (base >= (size_t)N_ALL*64) return;
  float4 v = *(const float4*)(finalbuf + base);
  if constexpr (sizeof(T)==2){
    u16x4 o; o[0]=f2bf(v.x); o[1]=f2bf(v.y); o[2]=f2bf(v.z); o[3]=f2bf(v.w);
    *(u16x4*)(out + base) = o;
  } else {
    *(float4*)((float*)out + base) = v;
  }
}

// ---------------- host pipeline (one per dtype; inactive one no-ops via flag) ----------------
template<typename T>
static void run_pipe(void* const* d_in, void* d_out, const int* flag,
                     float* finalbuf, float* msgTu, float* msgTi,
                     __bf16* gmsgT, __bf16* embTu, __bf16* embTi, hipStream_t stream)
{
  const T* ue  = (const T*)d_in[0];
  const T* ie  = (const T*)d_in[1];
  const T* ge  = (const T*)d_in[2];
  const T* uh  = (const T*)d_in[3];
  const T* ih  = (const T*)d_in[4];
  const T* fh  = (const T*)d_in[5];
  const T* qw1 = (const T*)d_in[8];
  const T* qb1 = (const T*)d_in[9];
  const T* qw2 = (const T*)d_in[10];
  const T* uw  = (const T*)d_in[11];
  const T* ub  = (const T*)d_in[12];
  const T* iw  = (const T*)d_in[13];
  const T* ib  = (const T*)d_in[14];

  init_emb_k<T><<<1407, 256, 0, stream>>>(flag, ue, ie, finalbuf, embTu, embTi);
  init_group_k<T><<<500, 256, 0, stream>>>(flag, ge, finalbuf, embTu);

  for (int l = 0; l < 2; l++){
    // zero msgTu + msgTi + gmsgT (contiguous in ws)
    hipMemsetAsync(msgTu, 0, (size_t)2*64*G_N*sizeof(float) + (size_t)64*LDG*2, stream);
    // user msg: M=2000 groups, K=30000 ; k-split 16, kLen=1920 (16*1920=30720>=30000)
    gemm_k<T,0><<<dim3(32,16), 256, 0, stream>>>(flag, uh, U_N, G_N, U_N,
                                                 embTu, LDU, 1920, msgTu, G_N, nullptr, nullptr);
    // item msg: K=60000 ; kLen=3840 (16*3840=61440>=60000)
    gemm_k<T,0><<<dim3(32,16), 256, 0, stream>>>(flag, ih, I_N, G_N, I_N,
                                                 embTi, LDI, 3840, msgTi, G_N, nullptr, nullptr);
    small_k<T><<<G_N, 64, 0, stream>>>(flag, msgTu, msgTi, ge,
        qw1 + (size_t)l*64*64, qb1 + (size_t)l*64, qw2 + (size_t)l*64,
        uw + (size_t)l*128*64, ub + (size_t)l*64,
        iw + (size_t)l*128*64, ib + (size_t)l*64,
        finalbuf, gmsgT);
    // node emb: M=90000, K=2000, no k-split; epilogue: final += , embT <- bf16
    gemm_k<T,1><<<dim3(1407,1), 256, 0, stream>>>(flag, fh, G_N, N_UI, G_N,
                                                  gmsgT, LDG, 2016, finalbuf, 64, embTu, embTi);
  }
  final_k<T><<<5750, 256, 0, stream>>>(flag, finalbuf, (T*)d_out);
}

extern "C" void kernel_launch(void* const* d_in, const int* in_sizes, int n_in,
                              void* d_out, int out_size, void* d_ws, size_t ws_size,
                              hipStream_t stream)
{
  (void)in_sizes; (void)n_in; (void)out_size;
  char* wsb = (char*)d_ws;
  constexpr size_t OFF_FINAL = 256;
  constexpr size_t SZ_FINAL  = (size_t)N_ALL*64*4;                 // 23,552,000
  constexpr size_t OFF_MSGU  = OFF_FINAL + SZ_FINAL;
  constexpr size_t OFF_MSGI  = OFF_MSGU + (size_t)64*G_N*4;        // +512,000
  constexpr size_t OFF_GMSG  = OFF_MSGI + (size_t)64*G_N*4;        // +512,000
  constexpr size_t OFF_EMBU  = OFF_GMSG + (size_t)64*LDG*2;        // +258,048
  constexpr size_t OFF_EMBI  = OFF_EMBU + (size_t)64*LDU*2;        // +3,842,048
  constexpr size_t NEED      = OFF_EMBI + (size_t)64*LDI*2;        // ~36.4 MB
  if (ws_size < NEED) return;

  int*    flag     = (int*)wsb;
  float*  finalbuf = (float*)(wsb + OFF_FINAL);
  float*  msgTu    = (float*)(wsb + OFF_MSGU);
  float*  msgTi    = (float*)(wsb + OFF_MSGI);
  __bf16* gmsgT    = (__bf16*)(wsb + OFF_GMSG);
  __bf16* embTu    = (__bf16*)(wsb + OFF_EMBU);
  __bf16* embTi    = (__bf16*)(wsb + OFF_EMBI);

  detect_k<<<1, 256, 0, stream>>>((const unsigned int*)d_in[3], flag);

  run_pipe<float>(d_in, d_out, flag, finalbuf, msgTu, msgTi, gmsgT, embTu, embTi, stream);
  run_pipe<unsigned short>(d_in, d_out, flag, finalbuf, msgTu, msgTi, gmsgT, embTu, embTi, stream);
}